// Round 1
// baseline (851.675 us; speedup 1.0000x reference)
//
#include <hip/hip_runtime.h>
#include <hip/hip_bf16.h>
#include <cstddef>
#include <cstdint>

#define B_  32
#define S_  50
#define L_  20
#define R_  16
#define D_  100
#define V_  50000
#define T_  320       // L_*R_
#define RD_ 1600      // R_*D_
#define BS_ 1600      // B_*S_

// ---------------- Phase A: x[bs][j] = sum_l emb0[stories[bs][r*20+l]][d] * in_mult[r*20+l][d]
__global__ __launch_bounds__(256) void x_kernel(
    const int* __restrict__ stories, const float* __restrict__ emb,
    const float* __restrict__ in_mult, float* __restrict__ x)
{
  __shared__ int toks[T_];
  int bs = blockIdx.x;
  const int* st = stories + (size_t)bs * T_;
  for (int t = threadIdx.x; t < T_; t += 256) toks[t] = st[t];
  __syncthreads();
  for (int j = threadIdx.x; j < RD_; j += 256) {
    int r = j / D_;
    int d = j - r * D_;
    float acc = 0.f;
    #pragma unroll
    for (int l = 0; l < 20; ++l) {
      int t = r * 20 + l;
      int tok = toks[t];
      if (tok != 0)
        acc += emb[(size_t)tok * D_ + d] * in_mult[t * D_ + d];
    }
    x[(size_t)bs * RD_ + j] = acc;
  }
}

// ---------------- transpose U [1600][100] -> Ut [100][1600]
__global__ void transpose_u_kernel(const float* __restrict__ U, float* __restrict__ Ut) {
  int o = blockIdx.x * 256 + threadIdx.x;
  if (o < RD_ * D_) {
    int k = o / RD_;
    int j = o - k * RD_;
    Ut[o] = U[(size_t)j * D_ + k];
  }
}

// ---------------- v_keys[j] = sum_k keys_flat[k] * Vw[j][k]  (one wave per j)
__global__ __launch_bounds__(256) void vkeys_kernel(
    const float* __restrict__ keys, const float* __restrict__ Vw, float* __restrict__ vk)
{
  int wave = threadIdx.x >> 6, lane = threadIdx.x & 63;
  int j = blockIdx.x * 4 + wave;
  float acc = 0.f;
  for (int k = lane; k < RD_; k += 64)
    acc += keys[k] * Vw[(size_t)j * RD_ + k];
  #pragma unroll
  for (int off = 32; off > 0; off >>= 1) acc += __shfl_down(acc, off);
  if (lane == 0) vk[j] = acc;
}

// ---------------- C[m][n] = sum_k A[m][k] * B[n][k]   (NT fp32 GEMM, 64x64 tile, TM=TN=4)
__global__ __launch_bounds__(256) void gemm_nt_kernel(
    const float* __restrict__ A, const float* __restrict__ B, float* __restrict__ C,
    int M, int N, int K)
{
  __shared__ __align__(16) float As[32][68];
  __shared__ __align__(16) float Bs[32][68];
  int tid = threadIdx.x;
  int bm = blockIdx.y * 64;
  int bn = blockIdx.x * 64;
  int tx = tid & 15;   // n sub-tile
  int ty = tid >> 4;   // m sub-tile
  float acc[4][4] = {};
  for (int kt = 0; kt < K; kt += 32) {
    #pragma unroll
    for (int i = 0; i < 2; ++i) {
      int f = tid + i * 256;          // 0..511
      int row = f >> 3, kc = f & 7;
      float4 a = *(const float4*)&A[(size_t)(bm + row) * K + kt + kc * 4];
      As[kc*4+0][row] = a.x; As[kc*4+1][row] = a.y;
      As[kc*4+2][row] = a.z; As[kc*4+3][row] = a.w;
      float4 b = *(const float4*)&B[(size_t)(bn + row) * K + kt + kc * 4];
      Bs[kc*4+0][row] = b.x; Bs[kc*4+1][row] = b.y;
      Bs[kc*4+2][row] = b.z; Bs[kc*4+3][row] = b.w;
    }
    __syncthreads();
    #pragma unroll
    for (int k = 0; k < 32; ++k) {
      float4 av = *(const float4*)&As[k][ty * 4];
      float4 bv = *(const float4*)&Bs[k][tx * 4];
      acc[0][0] += av.x*bv.x; acc[0][1] += av.x*bv.y; acc[0][2] += av.x*bv.z; acc[0][3] += av.x*bv.w;
      acc[1][0] += av.y*bv.x; acc[1][1] += av.y*bv.y; acc[1][2] += av.y*bv.z; acc[1][3] += av.y*bv.w;
      acc[2][0] += av.z*bv.x; acc[2][1] += av.z*bv.y; acc[2][2] += av.z*bv.z; acc[2][3] += av.z*bv.w;
      acc[3][0] += av.w*bv.x; acc[3][1] += av.w*bv.y; acc[3][2] += av.w*bv.z; acc[3][3] += av.w*bv.w;
    }
    __syncthreads();
  }
  #pragma unroll
  for (int i = 0; i < 4; ++i) {
    float4 v = make_float4(acc[i][0], acc[i][1], acc[i][2], acc[i][3]);
    *(float4*)&C[(size_t)(bm + ty*4 + i) * N + bn + tx*4] = v;
  }
}

// ---------------- scan: one block per batch element, 50 steps with __syncthreads
__global__ __launch_bounds__(1024) void scan_kernel(
    const float* __restrict__ x,       // [BS_][RD_]
    const float* __restrict__ Wall,    // [BS_][RD_]
    const float* __restrict__ Ut,      // [D_][RD_]
    const float* __restrict__ vkeys,   // [RD_]
    const float* __restrict__ keys,    // [RD_]  (R_ x D_)
    const float* __restrict__ init_state, // [D_]
    const float* __restrict__ alpha_in_p,
    float* __restrict__ state_out)     // [B_][D_]
{
  int b = blockIdx.x, tid = threadIdx.x;
  __shared__ float s_state[D_];
  __shared__ float s_keys[RD_];
  __shared__ float s_vk[RD_];
  __shared__ float s_c[RD_];
  float alpha = alpha_in_p[0];
  for (int j = tid; j < RD_; j += 1024) { s_keys[j] = keys[j]; s_vk[j] = vkeys[j]; }
  if (tid < D_) s_state[tid] = init_state[tid];
  __syncthreads();
  for (int s = 0; s < S_; ++s) {
    const float* xr = x    + ((size_t)b * S_ + s) * RD_;
    const float* wr = Wall + ((size_t)b * S_ + s) * RD_;
    for (int j = tid; j < RD_; j += 1024) {
      int r = j / D_;
      int d = j - r * D_;
      float sent = xr[j];
      // reference: sigmoid(sent*state + sent*keys)  (keep op order faithful)
      float z = sent * s_state[d] + sent * s_keys[j];
      float gate = 1.0f / (1.0f + expf(-z));
      float u = 0.f;
      #pragma unroll 4
      for (int k = 0; k < D_; ++k) u += s_state[k] * Ut[k * RD_ + j];
      float cand = u + s_vk[j] + wr[j];
      cand = cand >= 0.f ? cand : alpha * cand;
      s_c[j] = (gate == 0.5f) ? 0.f : cand * gate;
    }
    __syncthreads();
    if (tid < D_) {
      float csum = 0.f;
      #pragma unroll
      for (int r = 0; r < R_; ++r) csum += s_c[r * D_ + tid];
      float v = s_state[tid] + csum;
      v = v / sqrtf(v * v);   // torch.norm over singleton dim == |v|, faithful
      s_state[tid] = v;
    }
    __syncthreads();
  }
  if (tid < D_) state_out[(size_t)b * D_ + tid] = s_state[tid];
}

// ---------------- h[b][d] = prelu( q[b][d] + sum_k state[b][k]*Hw[d][k], alpha_q )
__global__ void head_kernel(
    const int* __restrict__ queries, const float* __restrict__ emb,
    const float* __restrict__ q_mult, const float* __restrict__ state_g,
    const float* __restrict__ Hw, const float* __restrict__ alpha_q_p,
    float* __restrict__ h_g)
{
  int b = blockIdx.x, d = threadIdx.x;
  if (d >= D_) return;
  float q = 0.f;
  #pragma unroll
  for (int l = 0; l < L_; ++l) {
    int tok = queries[b * L_ + l];
    if (tok != 0) q += emb[(size_t)tok * D_ + d] * q_mult[l * D_ + d];
  }
  float acc = 0.f;
  const float* st = state_g + (size_t)b * D_;
  #pragma unroll 4
  for (int k = 0; k < D_; ++k) acc += st[k] * Hw[(size_t)d * D_ + k];
  float h = q + acc;
  float alpha = alpha_q_p[0];
  h = h >= 0.f ? h : alpha * h;
  h_g[(size_t)b * D_ + d] = h;
}

// ---------------- out[b][v] = sum_k h[b][k] * Rw[v][k]   (v-tile=32 staged in LDS)
__global__ __launch_bounds__(256) void out_kernel(
    const float* __restrict__ h_g, const float* __restrict__ Rw, float* __restrict__ out)
{
  __shared__ __align__(16) float sh[B_ * D_];    // 3200
  __shared__ __align__(16) float sr[32 * D_];    // 3200
  int tid = threadIdx.x;
  int v0 = blockIdx.x * 32;
  for (int i = tid; i < B_ * D_; i += 256) sh[i] = h_g[i];
  int nrows = V_ - v0; if (nrows > 32) nrows = 32;
  for (int i = tid; i < nrows * D_; i += 256) sr[i] = Rw[(size_t)v0 * D_ + i];
  __syncthreads();
  const float4* sh4 = (const float4*)sh;
  const float4* sr4 = (const float4*)sr;
  int tv = (tid & 15) * 2;
  int tb = (tid >> 4) * 2;
  float a00 = 0.f, a01 = 0.f, a10 = 0.f, a11 = 0.f;
  #pragma unroll
  for (int kc = 0; kc < 25; ++kc) {
    float4 h0 = sh4[tb * 25 + kc];
    float4 h1 = sh4[(tb + 1) * 25 + kc];
    float4 r0 = sr4[tv * 25 + kc];
    float4 r1 = sr4[(tv + 1) * 25 + kc];
    a00 += h0.x*r0.x + h0.y*r0.y + h0.z*r0.z + h0.w*r0.w;
    a01 += h0.x*r1.x + h0.y*r1.y + h0.z*r1.z + h0.w*r1.w;
    a10 += h1.x*r0.x + h1.y*r0.y + h1.z*r0.z + h1.w*r0.w;
    a11 += h1.x*r1.x + h1.y*r1.y + h1.z*r1.z + h1.w*r1.w;
  }
  if (tv < nrows) {
    out[(size_t)tb * V_ + v0 + tv] = a00;
    out[(size_t)(tb + 1) * V_ + v0 + tv] = a10;
  }
  if (tv + 1 < nrows) {
    out[(size_t)tb * V_ + v0 + tv + 1] = a01;
    out[(size_t)(tb + 1) * V_ + v0 + tv + 1] = a11;
  }
}

extern "C" void kernel_launch(void* const* d_in, const int* in_sizes, int n_in,
                              void* d_out, int out_size, void* d_ws, size_t ws_size,
                              hipStream_t stream) {
  const int*   stories    = (const int*)  d_in[0];
  const int*   queries    = (const int*)  d_in[1];
  const float* emb        = (const float*)d_in[2];
  const float* in_mult    = (const float*)d_in[3];
  const float* q_mult     = (const float*)d_in[4];
  const float* keys       = (const float*)d_in[5];
  const float* init_state = (const float*)d_in[6];
  const float* U          = (const float*)d_in[7];
  const float* Vw         = (const float*)d_in[8];
  const float* Ww         = (const float*)d_in[9];
  const float* Hw         = (const float*)d_in[10];
  const float* Rw         = (const float*)d_in[11];
  const float* alpha_in   = (const float*)d_in[12];
  const float* alpha_q    = (const float*)d_in[13];
  float* out = (float*)d_out;

  char* ws = (char*)d_ws;
  float* x     = (float*)(ws);               // 2,560,000 f  (10,240,000 B)
  float* Wall  = (float*)(ws + 10240000);    // 2,560,000 f
  float* Ut    = (float*)(ws + 20480000);    //   160,000 f
  float* vk    = (float*)(ws + 21120000);    //     1,600 f
  float* state = (float*)(ws + 21126400);    //     3,200 f
  float* hbuf  = (float*)(ws + 21139200);    //     3,200 f
  // total 21,152,000 B of ws used

  x_kernel<<<BS_, 256, 0, stream>>>(stories, emb, in_mult, x);
  transpose_u_kernel<<<(RD_ * D_ + 255) / 256, 256, 0, stream>>>(U, Ut);
  vkeys_kernel<<<RD_ / 4, 256, 0, stream>>>(keys, Vw, vk);
  gemm_nt_kernel<<<dim3(RD_ / 64, BS_ / 64), 256, 0, stream>>>(x, Ww, Wall, BS_, RD_, RD_);
  scan_kernel<<<B_, 1024, 0, stream>>>(x, Wall, Ut, vk, keys, init_state, alpha_in, state);
  head_kernel<<<B_, 128, 0, stream>>>(queries, emb, q_mult, state, Hw, alpha_q, hbuf);
  out_kernel<<<(V_ + 31) / 32, 256, 0, stream>>>(hbuf, Rw, out);
}